// Round 11
// baseline (272.398 us; speedup 1.0000x reference)
//
#include <hip/hip_runtime.h>

typedef unsigned short u16;
typedef u16 u16x4 __attribute__((ext_vector_type(4)));
typedef u16 u16x8 __attribute__((ext_vector_type(8)));
typedef unsigned u32x2 __attribute__((ext_vector_type(2)));
typedef __bf16 bf16x8 __attribute__((ext_vector_type(8)));
typedef float f32x4 __attribute__((ext_vector_type(4)));

#define DEV static __device__ __forceinline__

DEV u16 f2bf(float f) {
  union { float f; unsigned u; } v; v.f = f;
  return (u16)((v.u + 0x7FFFu + ((v.u >> 16) & 1u)) >> 16);
}

// pack two fp32 -> two bf16 (round-half-up) into one u32
DEV unsigned pack2(float a, float b) {
  unsigned ua = __builtin_bit_cast(unsigned, a) + 0x8000u;
  unsigned ub = __builtin_bit_cast(unsigned, b) + 0x8000u;
  return (ua >> 16) | (ub & 0xFFFF0000u);
}

DEV void async16(const void* g, void* l) {
  __builtin_amdgcn_global_load_lds((const __attribute__((address_space(1))) void*)g,
                                   (__attribute__((address_space(3))) void*)l, 16, 0, 0);
}

DEV f32x4 mfma16(bf16x8 a, bf16x8 b, f32x4 c) {
  return __builtin_amdgcn_mfma_f32_16x16x32_bf16(a, b, c, 0, 0, 0);
}

DEV float exp2fast(float x) { return __builtin_amdgcn_exp2f(x); }  // v_exp_f32

// ------------- fused prep: pack x -> bf16 AND transpose-pack all weights ------------
// grid 9216 blocks: [0,8192) pack x; [8192,8960) Wq/Wk/Wv tpack; [8960,9216) pw tpack
// (replaces 5 launches -> 1: measured ~60-70us of inter-dispatch gap across rounds)
__global__ __launch_bounds__(256) void k_prep(const float* __restrict__ x,
                                              const float* __restrict__ Wk,
                                              const float* __restrict__ Wq,
                                              const float* __restrict__ Wv,
                                              const float* __restrict__ pw,
                                              u16* __restrict__ xb,
                                              u16* __restrict__ wT,
                                              u16* __restrict__ pwT) {
  __shared__ float t[64 * 72];
  const int bid = blockIdx.x, tid = threadIdx.x;
  if (bid < 8192) {                     // ---- pack x (fp32 -> bf16) ----
    int i = bid * 1024 + tid * 4;
    float4 v = *(const float4*)(x + i);
    u16x4 o = { f2bf(v.x), f2bf(v.y), f2bf(v.z), f2bf(v.w) };
    *(u16x4*)(xb + i) = o;
    return;
  }
  // ---- transpose-pack (rows x cols) fp32 -> bf16 [cols][rows], x scale ----
  const int role = bid - 8192;
  const float* src;
  u16* dst;
  int rows, cols, bx, by, bz;
  float scale;
  if (role < 768) {
    const int w = role >> 8, rem = role & 255;
    src = (w == 0) ? Wq : ((w == 1) ? Wk : Wv);
    dst = wT + (size_t)w * 1024 * 1024;
    scale = (w == 0) ? 1.44269504088896340736f : 1.0f;   // Q pre-scaled by log2e
    rows = 1024; cols = 64; bx = 0; by = rem >> 4; bz = rem & 15;
  } else {
    const int p = role - 768;
    src = pw; dst = pwT; scale = 1.0f;
    rows = 1024; cols = 1024; bx = p & 15; by = p >> 4; bz = 0;
  }
  src += (size_t)bz * rows * cols;
  dst += (size_t)bz * rows * cols;
  const int c0 = bx * 64, r0 = by * 64;
  const int rr = tid >> 2, cb = (tid & 3) * 16;
  const float* s = src + (size_t)(r0 + rr) * cols + c0 + cb;
  float4 v0 = *(const float4*)(s + 0);
  float4 v1 = *(const float4*)(s + 4);
  float4 v2 = *(const float4*)(s + 8);
  float4 v3 = *(const float4*)(s + 12);
  *(float4*)(t + rr * 72 + cb + 0)  = v0;
  *(float4*)(t + rr * 72 + cb + 4)  = v1;
  *(float4*)(t + rr * 72 + cb + 8)  = v2;
  *(float4*)(t + rr * 72 + cb + 12) = v3;
  __syncthreads();
  const int dd = tid >> 2, eb = (tid & 3) * 16;
  u16x8 o0, o1;
#pragma unroll
  for (int e = 0; e < 8; ++e) o0[e] = f2bf(t[(eb + e) * 72 + dd] * scale);
#pragma unroll
  for (int e = 0; e < 8; ++e) o1[e] = f2bf(t[(eb + 8 + e) * 72 + dd] * scale);
  u16* dp = dst + (size_t)(c0 + dd) * rows + r0 + eb;
  *(u16x8*)dp = o0;
  *(u16x8*)(dp + 8) = o1;
}

// ------------- GEMM v3: A[m][k] x Bt[n][k] bf16, K=1024, BK=64, swizzled staging ----
// NI = m-fragments per wave: 4 -> 128-row tile (r10-verified), 8 -> 256-row tile
// (cuts LDS reads/MFMA 0.5 -> 0.375 and staged bytes/MFMA by 25% -- QKV is LDS-bound).
// MODE 0: scatter bf16 into q/k [b][h][t][d]; V written TRANSPOSED -> vt [b][h][d][t]
// MODE 1: fp32 out[m][n] = acc + bias[n]
template <int MODE, int NI>
__global__ __launch_bounds__(256) void k_gemm(const u16* __restrict__ A,
                                              const u16* __restrict__ Bt,
                                              u16* __restrict__ qd,
                                              u16* __restrict__ kd,
                                              u16* __restrict__ vd,
                                              float* __restrict__ out,
                                              const float* __restrict__ bias) {
  __shared__ u16 As[NI * 32 * 64];   // NI*32 rows x 64 u16 (128B = full bank sweep)
  __shared__ u16 Bs[128 * 64];
  const int tid = threadIdx.x;
  const int wave = tid >> 6, lane = tid & 63;
  const int quad = lane >> 4, l15 = lane & 15;
  const int wm = wave & 1, wn = wave >> 1;
  const size_t mb = blockIdx.y, nb = blockIdx.x;

  // staging (r10-verified): inst m covers rows base + m*8 + (lane>>3),
  // 16B chunk (lane&7) ^ (lane>>3) applied on the GLOBAL address
  const int lrow = lane >> 3;
  const int lchunk = ((lane & 7) ^ lrow) << 3;
  const u16* ga = A + (mb * (NI * 32) + wave * (NI * 8) + lrow) * 1024 + lchunk;
  const u16* gb = Bt + (nb * 128 + wave * 32 + lrow) * 1024 + lchunk;
  u16* adst = As + wave * (NI * 512);
  u16* bdst = Bs + wave * 2048;

  // fragment reads: row stride 64 u16, phys chunk = (c*4+quad) ^ (l15&7)
  const int sa0 = ((0 + quad) ^ (l15 & 7)) << 3;
  const int sa1 = ((4 + quad) ^ (l15 & 7)) << 3;

  f32x4 acc[NI][4] = {};
  for (int k0 = 0; k0 < 1024; k0 += 64) {
#pragma unroll
    for (int m = 0; m < NI; ++m)
      async16(ga + m * 8 * 1024, adst + m * 512);
#pragma unroll
    for (int m = 0; m < 4; ++m)
      async16(gb + m * 8 * 1024, bdst + m * 512);
    ga += 64; gb += 64;
    __syncthreads();
#pragma unroll
    for (int c = 0; c < 2; ++c) {
      const int swz = c ? sa1 : sa0;
      bf16x8 af[NI], bf[4];
#pragma unroll
      for (int i = 0; i < NI; ++i)
        af[i] = *(const bf16x8*)(As + (wm * (NI * 16) + i * 16 + l15) * 64 + swz);
#pragma unroll
      for (int j = 0; j < 4; ++j)
        bf[j] = *(const bf16x8*)(Bs + (wn * 64 + j * 16 + l15) * 64 + swz);
#pragma unroll
      for (int i = 0; i < NI; ++i)
#pragma unroll
        for (int j = 0; j < 4; ++j)
          acc[i][j] = mfma16(af[i], bf[j], acc[i][j]);
    }
    __syncthreads();
  }

  const size_t m0 = mb * (NI * 32) + wm * (NI * 16);
  const int n0 = (int)nb * 128 + wn * 64;
  if (MODE == 0) {
#pragma unroll
    for (int j = 0; j < 4; ++j) {
      const int n = n0 + j * 16 + l15;
      const int p = n >> 10, hh = (n >> 6) & 15, d = n & 63;
      if (p == 2) {
#pragma unroll
        for (int i = 0; i < NI; ++i) {
          const size_t m = m0 + i * 16 + quad * 4;
          const size_t bb = m >> 11, tt = m & 2047;
          u16x4 pk = { f2bf(acc[i][j][0]), f2bf(acc[i][j][1]),
                       f2bf(acc[i][j][2]), f2bf(acc[i][j][3]) };
          *(u16x4*)(vd + ((bb * 16 + hh) * 64 + d) * 2048 + tt) = pk;
        }
      } else {
        u16* dst = (p == 0) ? qd : kd;
#pragma unroll
        for (int i = 0; i < NI; ++i)
#pragma unroll
          for (int r = 0; r < 4; ++r) {
            const size_t m = m0 + i * 16 + quad * 4 + r;
            const size_t bb = m >> 11, tt = m & 2047;
            dst[((bb * 16 + hh) * 2048 + tt) * 64 + d] = f2bf(acc[i][j][r]);
          }
      }
    }
  } else {
#pragma unroll
    for (int j = 0; j < 4; ++j) {
      const int n = n0 + j * 16 + l15;
      const float bv = bias[n];
#pragma unroll
      for (int i = 0; i < NI; ++i)
#pragma unroll
        for (int r = 0; r < 4; ++r) {
          const size_t m = m0 + i * 16 + quad * 4 + r;
          out[m * 1024 + n] = acc[i][j][r] + bv;
        }
    }
  }
}

// ------------- flash attention v9 (r9-verified): single qtile/block, 3 blocks/CU ----
// grid (BH, 16). Q [bh][t][d] (pre-scaled by log2e), K [bh][s][d], Vt [bh][d][t]
// out att [b][t][h*64+d] bf16
__global__ __launch_bounds__(256) void k_attn(const u16* __restrict__ Qg,
                                              const u16* __restrict__ Kg,
                                              const u16* __restrict__ Vtg,
                                              u16* __restrict__ Og) {
  __shared__ u16 Kbuf[2 * 4096];      // 16 KB, [buf][64 s][64 d] swizzled
  __shared__ u16 Vbuf[2 * 4096];      // 16 KB, [buf][64 d][64 t] swizzled
  __shared__ u16 Pbuf[4 * 32 * 72];   // 18 KB, per-wave P
  const int tid = threadIdx.x;
  const int wave = tid >> 6, lane = tid & 63;
  const int quad = lane >> 4, l15 = lane & 15;
  const int quad4 = quad * 4, quad8 = quad * 8;
  const int bh = blockIdx.x;
  const int qb = 15 - (int)blockIdx.y;             // heavy-first
  const u16* kg = Kg + (size_t)bh * 2048 * 64;
  const u16* vg = Vtg + (size_t)bh * 64 * 2048;
  u16* Pw = Pbuf + wave * (32 * 72);
  const int b = bh >> 4, h = bh & 15;

  const int lrow = lane >> 3;
  const int lchunk = ((lane & 7) ^ lrow) << 3;
  const u16* kst = kg + (size_t)(wave * 16 + lrow) * 64 + lchunk;
  const u16* vst = vg + (size_t)(wave * 16 + lrow) * 2048 + lchunk;
  u16* kdst0 = Kbuf + wave * 1024;
  u16* vdst0 = Vbuf + wave * 1024;

  const int rowoff = l15 * 64;
  const int swz0 = ((0 + quad) ^ (l15 & 7)) << 3;
  const int swz1 = ((4 + quad) ^ (l15 & 7)) << 3;

  const int qlo = qb * 128 + wave * 32;
  const int ntw = 2 * qb + 1 + (wave >> 1);        // this wave's valid tiles
  const int ntb = 2 * qb + 2;                      // block-uniform K-tile count
  const u16* qg = Qg + ((size_t)bh * 2048 + (size_t)qb * 128) * 64;

  bf16x8 qf[2][2];
#pragma unroll
  for (int i = 0; i < 2; ++i)
#pragma unroll
    for (int c = 0; c < 2; ++c)
      qf[i][c] = *(const bf16x8*)(qg + (size_t)(wave * 32 + i * 16 + l15) * 64 +
                                  c * 32 + quad8);

  f32x4 oacc[2][4] = {};
  float lsum[2] = {0.f, 0.f};
  const f32x4 fzero = {};

  // stage tile 0
  async16(kst, kdst0);
  async16(kst + 512, kdst0 + 512);
  async16(vst, vdst0);
  async16(vst + 16384, vdst0 + 512);

  for (int it = 0; it < ntb; ++it) {
    __syncthreads();   // vmcnt(0)+barrier: tile `it` staged

    if (it + 1 < ntb) {   // stage tile it+1 (overlaps compute below)
      const int buf = (it + 1) & 1;
      const size_t s0n = (size_t)(it + 1) * 64;
      async16(kst + s0n * 64,       kdst0 + buf * 4096);
      async16(kst + s0n * 64 + 512, kdst0 + buf * 4096 + 512);
      async16(vst + s0n,            vdst0 + buf * 4096);
      async16(vst + s0n + 16384,    vdst0 + buf * 4096 + 512);
    }

    if (it < ntw) {
      const int s0 = it * 64;
      const u16* Kb = Kbuf + (it & 1) * 4096;
      const u16* Vb = Vbuf + (it & 1) * 4096;

      // S^T = K * Q^T : D[m=s_local][n=q_local]
      f32x4 sacc[4][2];
#pragma unroll
      for (int j = 0; j < 4; ++j) {
        bf16x8 kf0 = *(const bf16x8*)(Kb + j * 1024 + rowoff + swz0);
        bf16x8 kf1 = *(const bf16x8*)(Kb + j * 1024 + rowoff + swz1);
        sacc[j][0] = mfma16(kf0, qf[0][0], fzero);
        sacc[j][0] = mfma16(kf1, qf[0][1], sacc[j][0]);
        sacc[j][1] = mfma16(kf0, qf[1][0], fzero);
        sacc[j][1] = mfma16(kf1, qf[1][1], sacc[j][1]);
      }

      // exp2 in-place (Q pre-scaled by log2e; scores bounded, no max needed)
#pragma unroll
      for (int j = 0; j < 4; ++j)
#pragma unroll
        for (int i = 0; i < 2; ++i)
#pragma unroll
          for (int r = 0; r < 4; ++r)
            sacc[j][i][r] = exp2fast(sacc[j][i][r]);

      if (it == ntw - 1) {   // causal mask: diagonal tile only
#pragma unroll
        for (int j = 0; j < 4; ++j)
#pragma unroll
          for (int i = 0; i < 2; ++i)
#pragma unroll
            for (int r = 0; r < 4; ++r)
              if (s0 + j * 16 + quad4 + r > qlo + i * 16 + l15) sacc[j][i][r] = 0.f;
      }

      // row-sum, bf16 pack, wave-private P store [q][s] stride 72
#pragma unroll
      for (int j = 0; j < 4; ++j)
#pragma unroll
        for (int i = 0; i < 2; ++i) {
          lsum[i] += (sacc[j][i][0] + sacc[j][i][1]) +
                     (sacc[j][i][2] + sacc[j][i][3]);
          u32x2 pk = { pack2(sacc[j][i][0], sacc[j][i][1]),
                       pack2(sacc[j][i][2], sacc[j][i][3]) };
          *(u32x2*)(Pw + (i * 16 + l15) * 72 + j * 16 + quad4) = pk;
        }

      // P A-fragments back from wave-private LDS (verified pattern)
      bf16x8 pa[2][2];
#pragma unroll
      for (int i = 0; i < 2; ++i)
#pragma unroll
        for (int c = 0; c < 2; ++c)
          pa[i][c] = *(const bf16x8*)(Pw + (i * 16 + l15) * 72 + c * 32 + quad8);

      // O += P * V
#pragma unroll
      for (int n = 0; n < 4; ++n) {
        bf16x8 vf0 = *(const bf16x8*)(Vb + n * 1024 + rowoff + swz0);
        bf16x8 vf1 = *(const bf16x8*)(Vb + n * 1024 + rowoff + swz1);
        oacc[0][n] = mfma16(pa[0][0], vf0, oacc[0][n]);
        oacc[0][n] = mfma16(pa[0][1], vf1, oacc[0][n]);
        oacc[1][n] = mfma16(pa[1][0], vf0, oacc[1][n]);
        oacc[1][n] = mfma16(pa[1][1], vf1, oacc[1][n]);
      }
    }
  }

  // combine quad-partial row sums (each quad holds a disjoint s-subset)
#pragma unroll
  for (int i = 0; i < 2; ++i) {
    lsum[i] += __shfl_xor(lsum[i], 16, 64);
    lsum[i] += __shfl_xor(lsum[i], 32, 64);
  }
#pragma unroll
  for (int i = 0; i < 2; ++i)
#pragma unroll
    for (int r = 0; r < 4; ++r) {
      const float inv = 1.0f / __shfl(lsum[i], quad4 + r, 16);
      const size_t t = (size_t)qb * 128 + wave * 32 + i * 16 + quad4 + r;
#pragma unroll
      for (int n = 0; n < 4; ++n)
        Og[((size_t)b * 2048 + t) * 1024 + h * 64 + n * 16 + l15] =
            f2bf(oacc[i][n][r] * inv);
    }
}

// ---------------- launch ----------------
extern "C" void kernel_launch(void* const* d_in, const int* in_sizes, int n_in,
                              void* d_out, int out_size, void* d_ws, size_t ws_size,
                              hipStream_t stream) {
  const float* x  = (const float*)d_in[0];
  const float* Wk = (const float*)d_in[1];
  const float* Wq = (const float*)d_in[2];
  const float* Wv = (const float*)d_in[3];
  const float* pw = (const float*)d_in[4];
  const float* pb = (const float*)d_in[5];
  float* out = (float*)d_out;
  char* ws = (char*)d_ws;

  u16* xb  = (u16*)(ws + 0);          // bf16 x [8192][1024]
  u16* wT  = (u16*)(ws + 16777216);   // bf16 [3072][1024]
  u16* pwT = (u16*)(ws + 23068672);   // bf16 [1024][1024]
  u16* q   = (u16*)(ws + 25165824);   // [bh][t][d] (pre-scaled by log2e)
  u16* kb  = (u16*)(ws + 41943040);   // [bh][s][d]
  u16* vt  = (u16*)(ws + 58720256);   // [bh][d][t]
  u16* att = (u16*)(ws + 0);          // aliases xb (xb dead after QKV GEMM)

  k_prep<<<9216, 256, 0, stream>>>(x, Wk, Wq, Wv, pw, xb, wT, pwT);
  k_gemm<0, 8><<<dim3(24, 32), 256, 0, stream>>>(xb, wT, q, kb, vt, nullptr, nullptr);
  k_attn<<<dim3(64, 16), 256, 0, stream>>>(q, kb, vt, att);
  k_gemm<1, 4><<<dim3(8, 64), 256, 0, stream>>>(att, pwT, nullptr, nullptr, nullptr, out, pb);
}

// Round 12
// 245.511 us; speedup vs baseline: 1.1095x; 1.1095x over previous
//
#include <hip/hip_runtime.h>

typedef unsigned short u16;
typedef u16 u16x4 __attribute__((ext_vector_type(4)));
typedef u16 u16x8 __attribute__((ext_vector_type(8)));
typedef unsigned u32x2 __attribute__((ext_vector_type(2)));
typedef __bf16 bf16x8 __attribute__((ext_vector_type(8)));
typedef float f32x4 __attribute__((ext_vector_type(4)));

#define DEV static __device__ __forceinline__

DEV u16 f2bf(float f) {
  union { float f; unsigned u; } v; v.f = f;
  return (u16)((v.u + 0x7FFFu + ((v.u >> 16) & 1u)) >> 16);
}

// pack two fp32 -> two bf16 (round-half-up) into one u32
DEV unsigned pack2(float a, float b) {
  unsigned ua = __builtin_bit_cast(unsigned, a) + 0x8000u;
  unsigned ub = __builtin_bit_cast(unsigned, b) + 0x8000u;
  return (ua >> 16) | (ub & 0xFFFF0000u);
}

DEV void async16(const void* g, void* l) {
  __builtin_amdgcn_global_load_lds((const __attribute__((address_space(1))) void*)g,
                                   (__attribute__((address_space(3))) void*)l, 16, 0, 0);
}

DEV f32x4 mfma16(bf16x8 a, bf16x8 b, f32x4 c) {
  return __builtin_amdgcn_mfma_f32_16x16x32_bf16(a, b, c, 0, 0, 0);
}

DEV float exp2fast(float x) { return __builtin_amdgcn_exp2f(x); }  // v_exp_f32

// ------------- fused prep: pack x -> bf16 AND transpose-pack all weights ------------
// grid 9216 blocks: [0,8192) pack x; [8192,8960) Wq/Wk/Wv tpack; [8960,9216) pw tpack
// (r11-verified: replaced 5 launches -> 1, saved ~38us of inter-dispatch gap)
__global__ __launch_bounds__(256) void k_prep(const float* __restrict__ x,
                                              const float* __restrict__ Wk,
                                              const float* __restrict__ Wq,
                                              const float* __restrict__ Wv,
                                              const float* __restrict__ pw,
                                              u16* __restrict__ xb,
                                              u16* __restrict__ wT,
                                              u16* __restrict__ pwT) {
  __shared__ float t[64 * 72];
  const int bid = blockIdx.x, tid = threadIdx.x;
  if (bid < 8192) {                     // ---- pack x (fp32 -> bf16) ----
    int i = bid * 1024 + tid * 4;
    float4 v = *(const float4*)(x + i);
    u16x4 o = { f2bf(v.x), f2bf(v.y), f2bf(v.z), f2bf(v.w) };
    *(u16x4*)(xb + i) = o;
    return;
  }
  // ---- transpose-pack (rows x cols) fp32 -> bf16 [cols][rows], x scale ----
  const int role = bid - 8192;
  const float* src;
  u16* dst;
  int rows, cols, bx, by, bz;
  float scale;
  if (role < 768) {
    const int w = role >> 8, rem = role & 255;
    src = (w == 0) ? Wq : ((w == 1) ? Wk : Wv);
    dst = wT + (size_t)w * 1024 * 1024;
    scale = (w == 0) ? 1.44269504088896340736f : 1.0f;   // Q pre-scaled by log2e
    rows = 1024; cols = 64; bx = 0; by = rem >> 4; bz = rem & 15;
  } else {
    const int p = role - 768;
    src = pw; dst = pwT; scale = 1.0f;
    rows = 1024; cols = 1024; bx = p & 15; by = p >> 4; bz = 0;
  }
  src += (size_t)bz * rows * cols;
  dst += (size_t)bz * rows * cols;
  const int c0 = bx * 64, r0 = by * 64;
  const int rr = tid >> 2, cb = (tid & 3) * 16;
  const float* s = src + (size_t)(r0 + rr) * cols + c0 + cb;
  float4 v0 = *(const float4*)(s + 0);
  float4 v1 = *(const float4*)(s + 4);
  float4 v2 = *(const float4*)(s + 8);
  float4 v3 = *(const float4*)(s + 12);
  *(float4*)(t + rr * 72 + cb + 0)  = v0;
  *(float4*)(t + rr * 72 + cb + 4)  = v1;
  *(float4*)(t + rr * 72 + cb + 8)  = v2;
  *(float4*)(t + rr * 72 + cb + 12) = v3;
  __syncthreads();
  const int dd = tid >> 2, eb = (tid & 3) * 16;
  u16x8 o0, o1;
#pragma unroll
  for (int e = 0; e < 8; ++e) o0[e] = f2bf(t[(eb + e) * 72 + dd] * scale);
#pragma unroll
  for (int e = 0; e < 8; ++e) o1[e] = f2bf(t[(eb + 8 + e) * 72 + dd] * scale);
  u16* dp = dst + (size_t)(c0 + dd) * rows + r0 + eb;
  *(u16x8*)dp = o0;
  *(u16x8*)(dp + 8) = o1;
}

// ------------- GEMM (r10-verified): A[m][k] x Bt[n][k] bf16, K=1024, 128x128, BK=64 -
// Swizzled staging (zero bank conflicts), 32KB LDS, VGPR 96 -> ~19% occupancy.
// r11 lesson: NI=8 (256-row tile, 48KB/168VGPR) collapsed residency to ~1 block/CU
// and halved MfmaUtil -- this workload needs >=8 resident waves/CU over fewer LDS ops.
// MODE 0: scatter bf16 into q/k [b][h][t][d]; V written TRANSPOSED -> vt [b][h][d][t]
// MODE 1: fp32 out[m][n] = acc + bias[n]
template <int MODE>
__global__ __launch_bounds__(256) void k_gemm(const u16* __restrict__ A,
                                              const u16* __restrict__ Bt,
                                              u16* __restrict__ qd,
                                              u16* __restrict__ kd,
                                              u16* __restrict__ vd,
                                              float* __restrict__ out,
                                              const float* __restrict__ bias) {
  __shared__ u16 As[128 * 64];   // 16 KB, swizzled
  __shared__ u16 Bs[128 * 64];   // 16 KB, swizzled
  const int tid = threadIdx.x;
  const int wave = tid >> 6, lane = tid & 63;
  const int quad = lane >> 4, l15 = lane & 15;
  const int wm = wave & 1, wn = wave >> 1;
  const size_t mb = blockIdx.y, nb = blockIdx.x;

  // staging: wave w, inst m covers rows w*32 + m*8 + (lane>>3), chunk (lane&7)^(lane>>3)
  const int lrow = lane >> 3;
  const int lchunk = ((lane & 7) ^ lrow) << 3;   // u16 offset within 64-u16 row
  const u16* ga = A + (mb * 128 + wave * 32 + lrow) * 1024 + lchunk;
  const u16* gb = Bt + (nb * 128 + wave * 32 + lrow) * 1024 + lchunk;
  u16* adst = As + wave * 2048;
  u16* bdst = Bs + wave * 2048;

  // fragment reads: row stride 64 u16 (128 B), phys chunk = (c*4+quad)^(l15&7)
  const int sa0 = ((0 + quad) ^ (l15 & 7)) << 3;
  const int sa1 = ((4 + quad) ^ (l15 & 7)) << 3;

  f32x4 acc[4][4] = {};
  for (int k0 = 0; k0 < 1024; k0 += 64) {
#pragma unroll
    for (int m = 0; m < 4; ++m) {
      async16(ga + m * 8 * 1024, adst + m * 512);
      async16(gb + m * 8 * 1024, bdst + m * 512);
    }
    ga += 64; gb += 64;
    __syncthreads();
#pragma unroll
    for (int c = 0; c < 2; ++c) {
      const int swz = c ? sa1 : sa0;
      bf16x8 af[4], bf[4];
#pragma unroll
      for (int i = 0; i < 4; ++i)
        af[i] = *(const bf16x8*)(As + (wm * 64 + i * 16 + l15) * 64 + swz);
#pragma unroll
      for (int j = 0; j < 4; ++j)
        bf[j] = *(const bf16x8*)(Bs + (wn * 64 + j * 16 + l15) * 64 + swz);
#pragma unroll
      for (int i = 0; i < 4; ++i)
#pragma unroll
        for (int j = 0; j < 4; ++j)
          acc[i][j] = mfma16(af[i], bf[j], acc[i][j]);
    }
    __syncthreads();
  }

  const size_t m0 = mb * 128 + wm * 64;
  const int n0 = (int)nb * 128 + wn * 64;
  if (MODE == 0) {
#pragma unroll
    for (int j = 0; j < 4; ++j) {
      const int n = n0 + j * 16 + l15;
      const int p = n >> 10, hh = (n >> 6) & 15, d = n & 63;
      if (p == 2) {
#pragma unroll
        for (int i = 0; i < 4; ++i) {
          const size_t m = m0 + i * 16 + quad * 4;
          const size_t bb = m >> 11, tt = m & 2047;
          u16x4 pk = { f2bf(acc[i][j][0]), f2bf(acc[i][j][1]),
                       f2bf(acc[i][j][2]), f2bf(acc[i][j][3]) };
          *(u16x4*)(vd + ((bb * 16 + hh) * 64 + d) * 2048 + tt) = pk;
        }
      } else {
        u16* dst = (p == 0) ? qd : kd;
#pragma unroll
        for (int i = 0; i < 4; ++i)
#pragma unroll
          for (int r = 0; r < 4; ++r) {
            const size_t m = m0 + i * 16 + quad * 4 + r;
            const size_t bb = m >> 11, tt = m & 2047;
            dst[((bb * 16 + hh) * 2048 + tt) * 64 + d] = f2bf(acc[i][j][r]);
          }
      }
    }
  } else {
#pragma unroll
    for (int j = 0; j < 4; ++j) {
      const int n = n0 + j * 16 + l15;
      const float bv = bias[n];
#pragma unroll
      for (int i = 0; i < 4; ++i)
#pragma unroll
        for (int r = 0; r < 4; ++r) {
          const size_t m = m0 + i * 16 + quad * 4 + r;
          out[m * 1024 + n] = acc[i][j][r] + bv;
        }
    }
  }
}

// ------------- flash attention v9 (r9-verified): single qtile/block, 3 blocks/CU ----
// grid (BH, 16). Q [bh][t][d] (pre-scaled by log2e), K [bh][s][d], Vt [bh][d][t]
// out att [b][t][h*64+d] bf16
__global__ __launch_bounds__(256) void k_attn(const u16* __restrict__ Qg,
                                              const u16* __restrict__ Kg,
                                              const u16* __restrict__ Vtg,
                                              u16* __restrict__ Og) {
  __shared__ u16 Kbuf[2 * 4096];      // 16 KB, [buf][64 s][64 d] swizzled
  __shared__ u16 Vbuf[2 * 4096];      // 16 KB, [buf][64 d][64 t] swizzled
  __shared__ u16 Pbuf[4 * 32 * 72];   // 18 KB, per-wave P
  const int tid = threadIdx.x;
  const int wave = tid >> 6, lane = tid & 63;
  const int quad = lane >> 4, l15 = lane & 15;
  const int quad4 = quad * 4, quad8 = quad * 8;
  const int bh = blockIdx.x;
  const int qb = 15 - (int)blockIdx.y;             // heavy-first
  const u16* kg = Kg + (size_t)bh * 2048 * 64;
  const u16* vg = Vtg + (size_t)bh * 64 * 2048;
  u16* Pw = Pbuf + wave * (32 * 72);
  const int b = bh >> 4, h = bh & 15;

  const int lrow = lane >> 3;
  const int lchunk = ((lane & 7) ^ lrow) << 3;
  const u16* kst = kg + (size_t)(wave * 16 + lrow) * 64 + lchunk;
  const u16* vst = vg + (size_t)(wave * 16 + lrow) * 2048 + lchunk;
  u16* kdst0 = Kbuf + wave * 1024;
  u16* vdst0 = Vbuf + wave * 1024;

  const int rowoff = l15 * 64;
  const int swz0 = ((0 + quad) ^ (l15 & 7)) << 3;
  const int swz1 = ((4 + quad) ^ (l15 & 7)) << 3;

  const int qlo = qb * 128 + wave * 32;
  const int ntw = 2 * qb + 1 + (wave >> 1);        // this wave's valid tiles
  const int ntb = 2 * qb + 2;                      // block-uniform K-tile count
  const u16* qg = Qg + ((size_t)bh * 2048 + (size_t)qb * 128) * 64;

  bf16x8 qf[2][2];
#pragma unroll
  for (int i = 0; i < 2; ++i)
#pragma unroll
    for (int c = 0; c < 2; ++c)
      qf[i][c] = *(const bf16x8*)(qg + (size_t)(wave * 32 + i * 16 + l15) * 64 +
                                  c * 32 + quad8);

  f32x4 oacc[2][4] = {};
  float lsum[2] = {0.f, 0.f};
  const f32x4 fzero = {};

  // stage tile 0
  async16(kst, kdst0);
  async16(kst + 512, kdst0 + 512);
  async16(vst, vdst0);
  async16(vst + 16384, vdst0 + 512);

  for (int it = 0; it < ntb; ++it) {
    __syncthreads();   // vmcnt(0)+barrier: tile `it` staged

    if (it + 1 < ntb) {   // stage tile it+1 (overlaps compute below)
      const int buf = (it + 1) & 1;
      const size_t s0n = (size_t)(it + 1) * 64;
      async16(kst + s0n * 64,       kdst0 + buf * 4096);
      async16(kst + s0n * 64 + 512, kdst0 + buf * 4096 + 512);
      async16(vst + s0n,            vdst0 + buf * 4096);
      async16(vst + s0n + 16384,    vdst0 + buf * 4096 + 512);
    }

    if (it < ntw) {
      const int s0 = it * 64;
      const u16* Kb = Kbuf + (it & 1) * 4096;
      const u16* Vb = Vbuf + (it & 1) * 4096;

      // S^T = K * Q^T : D[m=s_local][n=q_local]
      f32x4 sacc[4][2];
#pragma unroll
      for (int j = 0; j < 4; ++j) {
        bf16x8 kf0 = *(const bf16x8*)(Kb + j * 1024 + rowoff + swz0);
        bf16x8 kf1 = *(const bf16x8*)(Kb + j * 1024 + rowoff + swz1);
        sacc[j][0] = mfma16(kf0, qf[0][0], fzero);
        sacc[j][0] = mfma16(kf1, qf[0][1], sacc[j][0]);
        sacc[j][1] = mfma16(kf0, qf[1][0], fzero);
        sacc[j][1] = mfma16(kf1, qf[1][1], sacc[j][1]);
      }

      // exp2 in-place (Q pre-scaled by log2e; scores bounded, no max needed)
#pragma unroll
      for (int j = 0; j < 4; ++j)
#pragma unroll
        for (int i = 0; i < 2; ++i)
#pragma unroll
          for (int r = 0; r < 4; ++r)
            sacc[j][i][r] = exp2fast(sacc[j][i][r]);

      if (it == ntw - 1) {   // causal mask: diagonal tile only
#pragma unroll
        for (int j = 0; j < 4; ++j)
#pragma unroll
          for (int i = 0; i < 2; ++i)
#pragma unroll
            for (int r = 0; r < 4; ++r)
              if (s0 + j * 16 + quad4 + r > qlo + i * 16 + l15) sacc[j][i][r] = 0.f;
      }

      // row-sum, bf16 pack, wave-private P store [q][s] stride 72
#pragma unroll
      for (int j = 0; j < 4; ++j)
#pragma unroll
        for (int i = 0; i < 2; ++i) {
          lsum[i] += (sacc[j][i][0] + sacc[j][i][1]) +
                     (sacc[j][i][2] + sacc[j][i][3]);
          u32x2 pk = { pack2(sacc[j][i][0], sacc[j][i][1]),
                       pack2(sacc[j][i][2], sacc[j][i][3]) };
          *(u32x2*)(Pw + (i * 16 + l15) * 72 + j * 16 + quad4) = pk;
        }

      // P A-fragments back from wave-private LDS (verified pattern)
      bf16x8 pa[2][2];
#pragma unroll
      for (int i = 0; i < 2; ++i)
#pragma unroll
        for (int c = 0; c < 2; ++c)
          pa[i][c] = *(const bf16x8*)(Pw + (i * 16 + l15) * 72 + c * 32 + quad8);

      // O += P * V
#pragma unroll
      for (int n = 0; n < 4; ++n) {
        bf16x8 vf0 = *(const bf16x8*)(Vb + n * 1024 + rowoff + swz0);
        bf16x8 vf1 = *(const bf16x8*)(Vb + n * 1024 + rowoff + swz1);
        oacc[0][n] = mfma16(pa[0][0], vf0, oacc[0][n]);
        oacc[0][n] = mfma16(pa[0][1], vf1, oacc[0][n]);
        oacc[1][n] = mfma16(pa[1][0], vf0, oacc[1][n]);
        oacc[1][n] = mfma16(pa[1][1], vf1, oacc[1][n]);
      }
    }
  }

  // combine quad-partial row sums (each quad holds a disjoint s-subset)
#pragma unroll
  for (int i = 0; i < 2; ++i) {
    lsum[i] += __shfl_xor(lsum[i], 16, 64);
    lsum[i] += __shfl_xor(lsum[i], 32, 64);
  }
#pragma unroll
  for (int i = 0; i < 2; ++i)
#pragma unroll
    for (int r = 0; r < 4; ++r) {
      const float inv = 1.0f / __shfl(lsum[i], quad4 + r, 16);
      const size_t t = (size_t)qb * 128 + wave * 32 + i * 16 + quad4 + r;
#pragma unroll
      for (int n = 0; n < 4; ++n)
        Og[((size_t)b * 2048 + t) * 1024 + h * 64 + n * 16 + l15] =
            f2bf(oacc[i][n][r] * inv);
    }
}

// ---------------- launch ----------------
extern "C" void kernel_launch(void* const* d_in, const int* in_sizes, int n_in,
                              void* d_out, int out_size, void* d_ws, size_t ws_size,
                              hipStream_t stream) {
  const float* x  = (const float*)d_in[0];
  const float* Wk = (const float*)d_in[1];
  const float* Wq = (const float*)d_in[2];
  const float* Wv = (const float*)d_in[3];
  const float* pw = (const float*)d_in[4];
  const float* pb = (const float*)d_in[5];
  float* out = (float*)d_out;
  char* ws = (char*)d_ws;

  u16* xb  = (u16*)(ws + 0);          // bf16 x [8192][1024]
  u16* wT  = (u16*)(ws + 16777216);   // bf16 [3072][1024]
  u16* pwT = (u16*)(ws + 23068672);   // bf16 [1024][1024]
  u16* q   = (u16*)(ws + 25165824);   // [bh][t][d] (pre-scaled by log2e)
  u16* kb  = (u16*)(ws + 41943040);   // [bh][s][d]
  u16* vt  = (u16*)(ws + 58720256);   // [bh][d][t]
  u16* att = (u16*)(ws + 0);          // aliases xb (xb dead after QKV GEMM)

  k_prep<<<9216, 256, 0, stream>>>(x, Wk, Wq, Wv, pw, xb, wT, pwT);
  k_gemm<0><<<dim3(24, 64), 256, 0, stream>>>(xb, wT, q, kb, vt, nullptr, nullptr);
  k_attn<<<dim3(64, 16), 256, 0, stream>>>(q, kb, vt, att);
  k_gemm<1><<<dim3(8, 64), 256, 0, stream>>>(att, pwT, nullptr, nullptr, nullptr, out, pb);
}